// Round 9
// baseline (385.150 us; speedup 1.0000x reference)
//
#include <hip/hip_runtime.h>
#include <math.h>

// Problem constants (fixed by reference)
#define BB   2
#define TT   4096            // tokens per batch
#define NT   (BB*TT)         // 8192 total rows
#define DD   1024
#define CQ   128             // k_query dim
#define TK   8               // top_k
#define NCH  16              // s-splits (partial top-8 lists per query)

typedef __attribute__((ext_vector_type(8))) short short8b;  // 8 bf16 = 4 VGPR
typedef __attribute__((ext_vector_type(4))) float f32x4;

// strict insert: correct vs lax.top_k ties when candidates ascend in index
__device__ __forceinline__ void topk8_insert_strict(float (&v)[TK], int (&ix)[TK],
                                                    float val, int idx) {
    float cv = val; int ci = idx;
#pragma unroll
    for (int i = 0; i < TK; ++i) {
        bool sw = (cv > v[i]);
        float tv = v[i]; int ti = ix[i];
        v[i]  = sw ? cv : tv;  ix[i] = sw ? ci : ti;
        cv    = sw ? tv : cv;  ci    = sw ? ti : ci;
    }
}

// tie-break-aware insert (for merging lists whose index order is mixed)
__device__ __forceinline__ void topk8_insert(float (&v)[TK], int (&ix)[TK],
                                             float val, int idx) {
    float cv = val; int ci = idx;
#pragma unroll
    for (int i = 0; i < TK; ++i) {
        bool sw = (cv > v[i]) || (cv == v[i] && ci < ix[i]);
        float tv = v[i]; int ti = ix[i];
        v[i]  = sw ? cv : tv;  ix[i] = sw ? ci : ti;
        cv    = sw ? tv : cv;  ci    = sw ? ti : ci;
    }
}

__device__ __forceinline__ unsigned int pack_bf16(float a, float b) {
    unsigned int ua = __float_as_uint(a), ub = __float_as_uint(b);
    return (ua >> 16) | (ub & 0xFFFF0000u);
}

// ---------------------------------------------------------------------------
// K1: q = x@Wq + bq ; k = x@Wk + bk.  y-blocks reduced 16->8 (32 cols/thread)
// to halve redundant x traffic (537 -> 268 MB).
// ---------------------------------------------------------------------------
__global__ __launch_bounds__(256) void proj_kernel(
    const float* __restrict__ x,
    const float* __restrict__ Wq, const float* __restrict__ bq,
    const float* __restrict__ Wk, const float* __restrict__ bk,
    float* __restrict__ q, float* __restrict__ k)
{
    int row = blockIdx.x * 256 + threadIdx.x;        // 0..NT-1
    int cc  = blockIdx.y * 32;                       // combined col 0..255
    bool isK = cc >= CQ;
    const float* W    = isK ? Wk : Wq;
    const float* bias = isK ? bk : bq;
    int c0 = isK ? cc - CQ : cc;

    float acc[32];
#pragma unroll
    for (int j = 0; j < 32; ++j) acc[j] = 0.f;

    const float* xr = x + (size_t)row * DD;
    for (int d0 = 0; d0 < DD; d0 += 4) {
        float4 xv = *reinterpret_cast<const float4*>(xr + d0);
        const float* w0 = W + (size_t)d0 * CQ + c0;
#pragma unroll
        for (int j = 0; j < 32; ++j) {
            acc[j] = fmaf(xv.x, w0[j],        acc[j]);
            acc[j] = fmaf(xv.y, w0[CQ + j],   acc[j]);
            acc[j] = fmaf(xv.z, w0[2*CQ + j], acc[j]);
            acc[j] = fmaf(xv.w, w0[3*CQ + j], acc[j]);
        }
    }
    float* outp = (isK ? k : q) + (size_t)row * CQ + c0;
#pragma unroll
    for (int j = 0; j < 32; ++j) outp[j] = acc[j] + bias[c0 + j];
}

// ---------------------------------------------------------------------------
// K1b: gates = sigmoid(x@Wg + bg)   one wave per row (unchanged)
// ---------------------------------------------------------------------------
__global__ __launch_bounds__(256) void gate_kernel(
    const float* __restrict__ x, const float* __restrict__ Wg,
    const float* __restrict__ bg, float* __restrict__ gout)
{
    int wave = threadIdx.x >> 6, lane = threadIdx.x & 63;
    int row  = blockIdx.x * 4 + wave;
    const float* xr = x + (size_t)row * DD;
    float s = 0.f;
#pragma unroll
    for (int i = 0; i < 4; ++i) {
        int d = (i * 64 + lane) * 4;
        float4 xv = *reinterpret_cast<const float4*>(xr + d);
        float4 wv = *reinterpret_cast<const float4*>(Wg + d);
        s = fmaf(xv.x, wv.x, s); s = fmaf(xv.y, wv.y, s);
        s = fmaf(xv.z, wv.z, s); s = fmaf(xv.w, wv.w, s);
    }
#pragma unroll
    for (int off = 32; off; off >>= 1) s += __shfl_xor(s, off);
    if (lane == 0) gout[row] = 1.f / (1.f + expf(-(s + bg[0])));
}

// ---------------------------------------------------------------------------
// K2: MFMA bf16 candidate generation (unchanged from R8 — proven).
// ---------------------------------------------------------------------------
__global__ __launch_bounds__(256, 4) void simtopk_kernel(
    const float* __restrict__ qmat, const float* __restrict__ kmat,
    const float* __restrict__ gates, const float* __restrict__ am,
    int* __restrict__ pi)
{
    __shared__ unsigned int Qb[64 * 64];   // 16KB: row = 64 u32 (128 bf16)
    __shared__ unsigned int Kb[64 * 64];   // 16KB

    const int tid  = threadIdx.x;
    const int lane = tid & 63;
    const int wv   = tid >> 6;             // wave 0..3
    const int qt   = blockIdx.x;           // 0..127
    const int sp   = blockIdx.y;           // 0..15
    const int t0   = qt * 64;
    const int b    = t0 >> 12;

    const int sr = tid >> 2;               // 0..63
    const int sg0 = tid & 3;

    // ---- stage Qb once ----
    {
        const float* src = qmat + (size_t)(t0 + sr) * CQ;
#pragma unroll
        for (int j = 0; j < 4; ++j) {
            int g = sg0 + j * 4;
            float4 f0 = *reinterpret_cast<const float4*>(src + g * 8);
            float4 f1 = *reinterpret_cast<const float4*>(src + g * 8 + 4);
            uint4 u;
            u.x = pack_bf16(f0.x, f0.y); u.y = pack_bf16(f0.z, f0.w);
            u.z = pack_bf16(f1.x, f1.y); u.w = pack_bf16(f1.z, f1.w);
            *reinterpret_cast<uint4*>(&Qb[sr * 64 + ((g ^ (sr & 7)) << 2)]) = u;
        }
    }
    // ---- stage Kb chunk 0 ----
    {
        const float* src = kmat + (size_t)(b * TT + sp * 256 + sr) * CQ;
#pragma unroll
        for (int j = 0; j < 4; ++j) {
            int g = sg0 + j * 4;
            float4 f0 = *reinterpret_cast<const float4*>(src + g * 8);
            float4 f1 = *reinterpret_cast<const float4*>(src + g * 8 + 4);
            uint4 u;
            u.x = pack_bf16(f0.x, f0.y); u.y = pack_bf16(f0.z, f0.w);
            u.z = pack_bf16(f1.x, f1.y); u.w = pack_bf16(f1.z, f1.w);
            *reinterpret_cast<uint4*>(&Kb[sr * 64 + ((g ^ (sr & 7)) << 2)]) = u;
        }
    }

    const int l15  = lane & 15;
    const int l4   = lane >> 4;            // quarter 0..3
    const int qrow = wv * 16 + l15;        // query within block
    const int tq   = t0 + qrow;

    const float gate = gates[tq];
    const float mq   = am[tq];
    const float sgq  = 0.08838834764831845f * gate;
    const float mneg = -1e9f * gate;

    float tv[TK]; int tix[TK];
#pragma unroll
    for (int j = 0; j < TK; ++j) { tv[j] = -3.0e38f; tix[j] = 0; }

    const int koff = l4 * 4;
    __syncthreads();

    for (int ck = 0; ck < 4; ++ck) {
        f32x4 c0 = {0.f, 0.f, 0.f, 0.f};
        f32x4 c1 = {0.f, 0.f, 0.f, 0.f};
        f32x4 c2 = {0.f, 0.f, 0.f, 0.f};
        f32x4 c3 = {0.f, 0.f, 0.f, 0.f};
#pragma unroll
        for (int kb = 0; kb < 4; ++kb) {
            int gq = (kb * 4 + l4);
            short8b bq = *reinterpret_cast<const short8b*>(
                &Qb[qrow * 64 + (((gq) ^ (qrow & 7)) << 2)]);
            int r0 = l15,      p0 = ((gq) ^ (r0 & 7)) << 2;
            int r1 = 16 + l15, p1 = ((gq) ^ (r1 & 7)) << 2;
            int r2 = 32 + l15, p2 = ((gq) ^ (r2 & 7)) << 2;
            int r3 = 48 + l15, p3 = ((gq) ^ (r3 & 7)) << 2;
            short8b a0 = *reinterpret_cast<const short8b*>(&Kb[r0 * 64 + p0]);
            short8b a1 = *reinterpret_cast<const short8b*>(&Kb[r1 * 64 + p1]);
            short8b a2 = *reinterpret_cast<const short8b*>(&Kb[r2 * 64 + p2]);
            short8b a3 = *reinterpret_cast<const short8b*>(&Kb[r3 * 64 + p3]);
            c0 = __builtin_amdgcn_mfma_f32_16x16x32_bf16(a0, bq, c0, 0, 0, 0);
            c1 = __builtin_amdgcn_mfma_f32_16x16x32_bf16(a1, bq, c1, 0, 0, 0);
            c2 = __builtin_amdgcn_mfma_f32_16x16x32_bf16(a2, bq, c2, 0, 0, 0);
            c3 = __builtin_amdgcn_mfma_f32_16x16x32_bf16(a3, bq, c3, 0, 0, 0);
        }

        float4 pf[8];
        if (ck < 3) {
            const float* src = kmat +
                (size_t)(b * TT + sp * 256 + (ck + 1) * 64 + sr) * CQ;
#pragma unroll
            for (int j = 0; j < 4; ++j) {
                int g = sg0 + j * 4;
                pf[j * 2 + 0] = *reinterpret_cast<const float4*>(src + g * 8);
                pf[j * 2 + 1] = *reinterpret_cast<const float4*>(src + g * 8 + 4);
            }
        }

        {
            const int sB = sp * 256 + ck * 64;
            const float* amB = am + b * TT + sB;
            float val;
#define SCAN_TILE(CC, KT)                                                    \
            {                                                                \
                float4 amv = *reinterpret_cast<const float4*>(               \
                    amB + (KT) * 16 + koff);                                 \
                int kbase = sB + (KT) * 16 + koff;                           \
                val = (mq * amv.x == 0.f) ? mneg : CC.x * sgq;               \
                if (val > tv[TK-1]) topk8_insert_strict(tv, tix, val, kbase);\
                val = (mq * amv.y == 0.f) ? mneg : CC.y * sgq;               \
                if (val > tv[TK-1]) topk8_insert_strict(tv, tix, val, kbase+1);\
                val = (mq * amv.z == 0.f) ? mneg : CC.z * sgq;               \
                if (val > tv[TK-1]) topk8_insert_strict(tv, tix, val, kbase+2);\
                val = (mq * amv.w == 0.f) ? mneg : CC.w * sgq;               \
                if (val > tv[TK-1]) topk8_insert_strict(tv, tix, val, kbase+3);\
            }
            SCAN_TILE(c0, 0)
            SCAN_TILE(c1, 1)
            SCAN_TILE(c2, 2)
            SCAN_TILE(c3, 3)
#undef SCAN_TILE
        }
        __syncthreads();

        if (ck < 3) {
#pragma unroll
            for (int j = 0; j < 4; ++j) {
                int g = sg0 + j * 4;
                uint4 u;
                u.x = pack_bf16(pf[j*2].x, pf[j*2].y);
                u.y = pack_bf16(pf[j*2].z, pf[j*2].w);
                u.z = pack_bf16(pf[j*2+1].x, pf[j*2+1].y);
                u.w = pack_bf16(pf[j*2+1].z, pf[j*2+1].w);
                *reinterpret_cast<uint4*>(&Kb[sr * 64 + ((g ^ (sr & 7)) << 2)]) = u;
            }
        }
        __syncthreads();
    }

    // ---- merge the 4 lane-quarters per query (tie-aware) ----
    float* mv = reinterpret_cast<float*>(Qb);
    int*   mi = reinterpret_cast<int*>(Kb);
    int slot = qrow * 4 + l4;
#pragma unroll
    for (int j = 0; j < TK; ++j) { mv[slot * 9 + j] = tv[j]; mi[slot * 9 + j] = tix[j]; }
    __syncthreads();
    if (l4 == 0) {
        for (int u = 1; u < 4; ++u) {
#pragma unroll
            for (int j = 0; j < TK; ++j) {
                float val = mv[(slot + u) * 9 + j];
                int   s   = mi[(slot + u) * 9 + j];
                if (val > tv[TK-1] || (val == tv[TK-1] && s < tix[TK-1]))
                    topk8_insert(tv, tix, val, s);
            }
        }
        int base = (tq * NCH + sp) * TK;
#pragma unroll
        for (int j = 0; j < TK; ++j) pi[base + j] = tix[j];
    }
}

// ---------------------------------------------------------------------------
// K3: fully parallel exact ranking + gather.
//  - rescore: 2 threads/candidate, 64 dims each, 4 f64 partial accs (fixed
//    combine order -> deterministic & ~exact), halves merged via shfl_xor(1).
//  - rank: 128 candidates are DISTINCT (disjoint splits/quarters), total
//    order (value desc, idx asc) -> each thread counts beats; rank<8 writes
//    its slot directly. No serial merge.
// ---------------------------------------------------------------------------
__global__ __launch_bounds__(256) void merge_gather_kernel(
    const float* __restrict__ x,  const float* __restrict__ qm,
    const float* __restrict__ kmat, const float* __restrict__ gates,
    const float* __restrict__ am, const int* __restrict__ pi,
    float* __restrict__ out_g, float* __restrict__ out_i,
    float* __restrict__ out_v)
{
    int t = blockIdx.x;
    int b = t >> 12;
    int tid = threadIdx.x;

    __shared__ float  qrow[CQ];
    __shared__ double svald[NCH * TK];
    __shared__ int    scand[NCH * TK];
    __shared__ int    fidx[TK];

    if (tid < 32) {
        *reinterpret_cast<float4*>(qrow + tid * 4) =
            *reinterpret_cast<const float4*>(qm + (size_t)t * CQ + tid * 4);
    }
    __syncthreads();

    // ---- rescore: c = tid>>1, half = tid&1 handles dims half*64..+63 ----
    {
        int c    = tid >> 1;
        int half = tid & 1;
        int s = pi[(size_t)t * NCH * TK + c];
        const float* kr = kmat + (size_t)(b * TT + s) * CQ + half * 64;
        const float* qh = qrow + half * 64;
        double a0 = 0.0, a1 = 0.0, a2 = 0.0, a3 = 0.0;
#pragma unroll
        for (int d = 0; d < 64; d += 4) {
            float4 kv = *reinterpret_cast<const float4*>(kr + d);
            a0 += (double)qh[d + 0] * (double)kv.x;
            a1 += (double)qh[d + 1] * (double)kv.y;
            a2 += (double)qh[d + 2] * (double)kv.z;
            a3 += (double)qh[d + 3] * (double)kv.w;
        }
        double mine  = (a0 + a1) + (a2 + a3);
        double other = __shfl_xor(mine, 1);
        double lo = half ? other : mine;
        double hi = half ? mine  : other;
        double acc = lo + hi;                       // identical on both lanes
        if (half == 0) {
            float ms  = am[b * TT + s];
            float mqq = am[t];
            double val = (mqq * ms == 0.f) ? -1e9 : acc * 0.08838834764831845;
            val *= (double)gates[t];
            svald[c] = val;
            scand[c] = s;
        }
    }
    __syncthreads();

    // ---- all-pairs rank (parallel top-8) ----
    if (tid < NCH * TK) {
        double v = svald[tid]; int si = scand[tid];
        int rank = 0;
        for (int c2 = 0; c2 < NCH * TK; ++c2) {
            double v2 = svald[c2]; int s2 = scand[c2];
            rank += (v2 > v) || (v2 == v && s2 < si);
        }
        if (rank < TK) {
            out_i[t * TK + rank] = (float)si;
            out_v[t * TK + rank] = (float)v;
            fidx[rank] = si;
        }
    }
    __syncthreads();

    // ---- gather 8 x-rows ----
#pragma unroll
    for (int j = 0; j < TK; ++j) {
        int row = fidx[j];
        float4 val4 = *reinterpret_cast<const float4*>(
            x + ((size_t)(b * TT + row)) * DD + tid * 4);
        *reinterpret_cast<float4*>(
            out_g + ((size_t)(t * TK + j)) * DD + tid * 4) = val4;
    }
}

// ---------------------------------------------------------------------------
extern "C" void kernel_launch(void* const* d_in, const int* in_sizes, int n_in,
                              void* d_out, int out_size, void* d_ws, size_t ws_size,
                              hipStream_t stream) {
    const float* x  = (const float*)d_in[0];
    const float* am = (const float*)d_in[1];
    const float* Wq = (const float*)d_in[2];
    const float* bq = (const float*)d_in[3];
    const float* Wk = (const float*)d_in[4];
    const float* bk = (const float*)d_in[5];
    const float* Wg = (const float*)d_in[6];
    const float* bg = (const float*)d_in[7];

    float* ws = (float*)d_ws;
    float* q  = ws;                              // NT*CQ      = 1048576
    float* k  = ws + 1048576;                    // NT*CQ      = 1048576
    float* g  = ws + 2097152;                    // NT         = 8192
    int*   pi = (int*)(ws + 2105344);            // NT*NCH*TK  = 1048576

    float* out_g = (float*)d_out;                // [B,T,K,D] = 67108864
    float* out_i = out_g + 67108864;             // [B,T,K]   = 65536 (as float)
    float* out_v = out_i + 65536;                // [B,T,K]   = 65536

    proj_kernel<<<dim3(NT / 256, 8), 256, 0, stream>>>(x, Wq, bq, Wk, bk, q, k);
    gate_kernel<<<NT / 4, 256, 0, stream>>>(x, Wg, bg, g);
    simtopk_kernel<<<dim3(128, NCH), 256, 0, stream>>>(q, k, g, am, pi);
    merge_gather_kernel<<<NT, 256, 0, stream>>>(x, q, k, g, am, pi,
                                                out_g, out_i, out_v);
}